// Round 1
// baseline (5212.886 us; speedup 1.0000x reference)
//
#include <hip/hip_runtime.h>

typedef _Float16 half2_t __attribute__((ext_vector_type(2)));
typedef _Float16 half8_t __attribute__((ext_vector_type(8)));
typedef float floatx4 __attribute__((ext_vector_type(4)));
typedef unsigned int u32;

#define BB 64
#define TT 2048
#define II 128
#define HH 256
#define CC 64
#define G3 (3*HH)          // 768
#define MTOT (BB*TT)       // 131072

static __device__ __forceinline__ float dot2f(half2_t a, half2_t b, float c) {
#if __has_builtin(__builtin_amdgcn_fdot2)
    return __builtin_amdgcn_fdot2(a, b, c, false);
#else
    return c + (float)a[0]*(float)b[0] + (float)a[1]*(float)b[1];
#endif
}

// ---------------------------------------------------------------------------
// MFMA GEMM: C[M,N] = A[M,K] @ W[N,K]^T + bias.
// f16 inputs (converted on stage), fp32 accum via v_mfma_f32_16x16x32_f16.
// Tile: BM=128, BN=64, BK=64. 256 threads = 4 waves in 2x2 layout; each wave
// owns a 64x32 output region = 4x2 fragments of 16x16.
// LDS: 16B-slot XOR swizzle (slot ^= row&7) -> conflict-free ds_read_b128
// for both the k-contiguous fragment reads and the staging writes.
// A and B fragments use the SAME (lanegroup,elem)->k mapping (8 contiguous k
// per lane), so the MFMA-internal k-permutation cancels between A and B.
// C/D layout (HW-verified): col = lane&15, row = (lane>>4)*4 + reg.
// blockIdx.x = n-tile (fast) so consecutive blocks share the A m-tile in L2.
// ---------------------------------------------------------------------------
template<typename AT, typename CT>
__global__ __launch_bounds__(256, 2)
void gemm_mfma(const AT* __restrict__ A, const float* __restrict__ W,
               const float* __restrict__ bias, CT* __restrict__ Cout,
               int M, int N, int K)
{
    __shared__ alignas(16) u32 As32[128 * 32];   // [row][8 slots of 16B], swizzled
    __shared__ alignas(16) u32 Bs32[64 * 32];

    const int tid  = threadIdx.x;
    const int lane = tid & 63;
    const int wave = tid >> 6;        // 0..3
    const int wm   = wave >> 1;       // 0..1 -> m offset 64*wm
    const int wn   = wave & 1;        // 0..1 -> n offset 32*wn
    const int m0   = blockIdx.y * 128;
    const int n0   = blockIdx.x * 64;
    const int lr   = lane & 15;       // fragment row/col
    const int lg   = lane >> 4;       // k-group 0..3

    floatx4 acc[4][2] = {};

    for (int kc = 0; kc < K; kc += 64) {
        // ---- stage A: 128 rows x 64 f16 = 1024 x 16B slots, 4 iters ----
        #pragma unroll
        for (int it = 0; it < 4; ++it) {
            const int s    = it * 256 + tid;
            const int row  = s >> 3;          // 0..127
            const int slot = s & 7;           // 0..7 (8 f16 each)
            const AT* src  = A + (size_t)(m0 + row) * K + kc + slot * 8;
            half8_t v;
            if constexpr (sizeof(AT) == 2) {
                v = *reinterpret_cast<const half8_t*>(src);
            } else {
                const float4* s4 = reinterpret_cast<const float4*>(src);
                float4 lo = s4[0], hi = s4[1];
                v[0] = (_Float16)lo.x; v[1] = (_Float16)lo.y;
                v[2] = (_Float16)lo.z; v[3] = (_Float16)lo.w;
                v[4] = (_Float16)hi.x; v[5] = (_Float16)hi.y;
                v[6] = (_Float16)hi.z; v[7] = (_Float16)hi.w;
            }
            const int sw = slot ^ (row & 7);
            *reinterpret_cast<half8_t*>(&As32[row * 32 + sw * 4]) = v;
        }
        // ---- stage B: 64 rows x 64 f16 = 512 slots, 2 iters (fp32 W) ----
        #pragma unroll
        for (int it = 0; it < 2; ++it) {
            const int s    = it * 256 + tid;
            const int row  = s >> 3;          // 0..63
            const int slot = s & 7;
            const float* src = W + (size_t)(n0 + row) * K + kc + slot * 8;
            const float4* s4 = reinterpret_cast<const float4*>(src);
            float4 lo = s4[0], hi = s4[1];
            half8_t v;
            v[0] = (_Float16)lo.x; v[1] = (_Float16)lo.y;
            v[2] = (_Float16)lo.z; v[3] = (_Float16)lo.w;
            v[4] = (_Float16)hi.x; v[5] = (_Float16)hi.y;
            v[6] = (_Float16)hi.z; v[7] = (_Float16)hi.w;
            const int sw = slot ^ (row & 7);
            *reinterpret_cast<half8_t*>(&Bs32[row * 32 + sw * 4]) = v;
        }
        __syncthreads();

        #pragma unroll
        for (int ks = 0; ks < 2; ++ks) {
            half8_t af[4], bf[2];
            #pragma unroll
            for (int fm = 0; fm < 4; ++fm) {
                const int row  = wm * 64 + fm * 16 + lr;
                const int slot = ks * 4 + lg;
                const int sw   = slot ^ (row & 7);
                af[fm] = *reinterpret_cast<const half8_t*>(&As32[row * 32 + sw * 4]);
            }
            #pragma unroll
            for (int fn = 0; fn < 2; ++fn) {
                const int row  = wn * 32 + fn * 16 + lr;
                const int slot = ks * 4 + lg;
                const int sw   = slot ^ (row & 7);
                bf[fn] = *reinterpret_cast<const half8_t*>(&Bs32[row * 32 + sw * 4]);
            }
            #pragma unroll
            for (int fm = 0; fm < 4; ++fm)
                #pragma unroll
                for (int fn = 0; fn < 2; ++fn)
                    acc[fm][fn] = __builtin_amdgcn_mfma_f32_16x16x32_f16(
                        af[fm], bf[fn], acc[fm][fn], 0, 0, 0);
        }
        __syncthreads();
    }

    // ---- epilogue: D[row=(lane>>4)*4+reg][col=lane&15] + bias ----
    #pragma unroll
    for (int fn = 0; fn < 2; ++fn) {
        const int n = n0 + wn * 32 + fn * 16 + lr;
        const float bv = bias[n];
        #pragma unroll
        for (int fm = 0; fm < 4; ++fm) {
            #pragma unroll
            for (int r = 0; r < 4; ++r) {
                const int m = m0 + wm * 64 + fm * 16 + lg * 4 + r;
                Cout[(size_t)m * N + n] = (CT)(acc[fm][fn][r] + bv);
            }
        }
    }
}

// ---------------------------------------------------------------------------
// Persistent GRU scan. One WG per batch element, 512 threads (8 waves).
// Thread t: row j = t>>1 (0..255), k-half kh = t&1. Holds W_hh rows
// {j, 256+j, 512+j} for its k-half as f16 pairs in VGPRs (192 regs).
// h (256 f16) lives in LDS; per step each thread reads its 128-value half
// via 16 ds_read_b128 (2 distinct addrs per wave -> broadcast, free),
// does 192 v_dot2_f32_f16, reduces the k-halves via shfl_xor(1), applies
// the GRU gate math, and threads t%4==0 write the packed new h to LDS +
// the layer output (f16, consumed by the next phase's GEMM).
// ---------------------------------------------------------------------------
__global__ __launch_bounds__(512, 2)
void gru_scan(const _Float16* __restrict__ gx,   // [B, T, 768] incl. b_ih
              const float* __restrict__ Whh,     // [768, 256]
              const float* __restrict__ bhh,     // [768]
              _Float16* __restrict__ hout)       // [B, T, 256]
{
    const int b  = blockIdx.x;
    const int t  = threadIdx.x;
    const int j  = t >> 1;
    const int kh = t & 1;

    half2_t w0[64], w1[64], w2[64];
    {
        const float* p0 = Whh + (size_t)j * HH + kh * 128;
        const float* p1 = p0 + 256 * HH;
        const float* p2 = p0 + 512 * HH;
        #pragma unroll
        for (int i = 0; i < 64; ++i) {
            w0[i] = half2_t{(_Float16)p0[2*i], (_Float16)p0[2*i+1]};
            w1[i] = half2_t{(_Float16)p1[2*i], (_Float16)p1[2*i+1]};
            w2[i] = half2_t{(_Float16)p2[2*i], (_Float16)p2[2*i+1]};
        }
    }
    const float bh_r = bhh[j], bh_z = bhh[HH + j], bh_n = bhh[2*HH + j];

    __shared__ alignas(16) u32 h2[HH/2];   // 256 f16 packed
    if (t < HH/2) h2[t] = 0u;
    float hprev = 0.f;
    __syncthreads();

    const _Float16* g = gx + (size_t)b * TT * G3;
    u32* op = (u32*)(hout + (size_t)b * TT * HH);

    for (int step = 0; step < TT; ++step) {
        // input-side gate preactivations (loads issue early, hidden by dots)
        float xr = (float)g[j];
        float xz = (float)g[HH + j];
        float xn = (float)g[2*HH + j];

        const uint4* hb = (const uint4*)(h2 + kh * 64);
        float ar = 0.f, az = 0.f, an = 0.f;
        #pragma unroll
        for (int c = 0; c < 16; ++c) {
            uint4 hv = hb[c];
            half2_t ha = __builtin_bit_cast(half2_t, hv.x);
            half2_t hc = __builtin_bit_cast(half2_t, hv.y);
            half2_t hd = __builtin_bit_cast(half2_t, hv.z);
            half2_t he = __builtin_bit_cast(half2_t, hv.w);
            ar = dot2f(ha, w0[4*c+0], ar); az = dot2f(ha, w1[4*c+0], az); an = dot2f(ha, w2[4*c+0], an);
            ar = dot2f(hc, w0[4*c+1], ar); az = dot2f(hc, w1[4*c+1], az); an = dot2f(hc, w2[4*c+1], an);
            ar = dot2f(hd, w0[4*c+2], ar); az = dot2f(hd, w1[4*c+2], az); an = dot2f(hd, w2[4*c+2], an);
            ar = dot2f(he, w0[4*c+3], ar); az = dot2f(he, w1[4*c+3], az); an = dot2f(he, w2[4*c+3], an);
        }
        // combine the two k-halves (partner lane = t^1, same wave)
        ar += __shfl_xor(ar, 1);
        az += __shfl_xor(az, 1);
        an += __shfl_xor(an, 1);

        const float r = 1.f / (1.f + __expf(-(xr + ar + bh_r)));
        const float z = 1.f / (1.f + __expf(-(xz + az + bh_z)));
        const float e = __expf(2.f * (xn + r * (an + bh_n)));
        const float n = 1.f - 2.f / (e + 1.f);
        const float hnew = (1.f - z) * n + z * hprev;
        hprev = hnew;

        const float hother = __shfl_xor(hnew, 2);   // row j^1 (lane t^2)
        __syncthreads();                             // all h2 reads done
        if ((t & 3) == 0) {                          // j even, kh 0: owns pair j/2
            half2_t hp{(_Float16)hnew, (_Float16)hother};
            const u32 pu = __builtin_bit_cast(u32, hp);
            h2[t >> 2] = pu;
            op[t >> 2] = pu;
        }
        __syncthreads();
        g  += G3;
        op += HH/2;
    }
}

// ---------------------------------------------------------------------------
extern "C" void kernel_launch(void* const* d_in, const int* in_sizes, int n_in,
                              void* d_out, int out_size, void* d_ws, size_t ws_size,
                              hipStream_t stream) {
    const float* x    = (const float*)d_in[0];
    const float* Wih0 = (const float*)d_in[1];
    const float* Whh0 = (const float*)d_in[2];
    const float* bih0 = (const float*)d_in[3];
    const float* bhh0 = (const float*)d_in[4];
    const float* Wih1 = (const float*)d_in[5];
    const float* Whh1 = (const float*)d_in[6];
    const float* bih1 = (const float*)d_in[7];
    const float* bhh1 = (const float*)d_in[8];
    const float* fcw  = (const float*)d_in[9];
    const float* fcb  = (const float*)d_in[10];
    float* out = (float*)d_out;

    // workspace: gx buffer (192 MB, reused for both layers) + h buffer (64 MB)
    _Float16* gxbuf = (_Float16*)d_ws;
    _Float16* hbuf  = (_Float16*)((char*)d_ws + (size_t)MTOT * G3 * sizeof(_Float16));

    const dim3 blk(256);
    // 1) gx0 = x @ W_ih0^T + b_ih0
    gemm_mfma<float, _Float16><<<dim3(G3/64, MTOT/128), blk, 0, stream>>>(
        x, Wih0, bih0, gxbuf, MTOT, G3, II);
    // 2) scan layer 0 -> h0
    gru_scan<<<dim3(BB), dim3(512), 0, stream>>>(gxbuf, Whh0, bhh0, hbuf);
    // 3) gx1 = h0 @ W_ih1^T + b_ih1 (overwrites gx buffer)
    gemm_mfma<_Float16, _Float16><<<dim3(G3/64, MTOT/128), blk, 0, stream>>>(
        hbuf, Wih1, bih1, gxbuf, MTOT, G3, HH);
    // 4) scan layer 1 -> h1 (overwrites h buffer)
    gru_scan<<<dim3(BB), dim3(512), 0, stream>>>(gxbuf, Whh1, bhh1, hbuf);
    // 5) out = h1 @ fc_w^T + fc_b
    gemm_mfma<_Float16, float><<<dim3(CC/64, MTOT/128), blk, 0, stream>>>(
        hbuf, fcw, fcb, out, MTOT, CC, HH);
}

// Round 2
// 5106.274 us; speedup vs baseline: 1.0209x; 1.0209x over previous
//
#include <hip/hip_runtime.h>

typedef _Float16 half2_t __attribute__((ext_vector_type(2)));
typedef _Float16 half8_t __attribute__((ext_vector_type(8)));
typedef float floatx4 __attribute__((ext_vector_type(4)));
typedef unsigned int u32;

#define BB 64
#define TT 2048
#define II 128
#define HH 256
#define CC 64
#define G3 (3*HH)          // 768
#define MTOT (BB*TT)       // 131072

static __device__ __forceinline__ float dot2f(half2_t a, half2_t b, float c) {
#if __has_builtin(__builtin_amdgcn_fdot2)
    return __builtin_amdgcn_fdot2(a, b, c, false);
#else
    return c + (float)a[0]*(float)b[0] + (float)a[1]*(float)b[1];
#endif
}

static __device__ __forceinline__ half2_t bch2(u32 x) {
    return __builtin_bit_cast(half2_t, x);
}

// quad butterfly sum: after both stages all 4 lanes of each quad hold the sum.
// quad_perm [1,0,3,2] = 0xB1 (xor 1), quad_perm [2,3,0,1] = 0x4E (xor 2).
static __device__ __forceinline__ float quad_allsum(float x) {
    int i = __builtin_bit_cast(int, x);
    int a = __builtin_amdgcn_mov_dpp(i, 0xB1, 0xF, 0xF, true);
    float y = x + __builtin_bit_cast(float, a);
    int k = __builtin_bit_cast(int, y);
    int b = __builtin_amdgcn_mov_dpp(k, 0x4E, 0xF, 0xF, true);
    return y + __builtin_bit_cast(float, b);
}

static __device__ __forceinline__ float fast_rcp(float x) {
    return __builtin_amdgcn_rcpf(x);
}

// ---------------------------------------------------------------------------
// MFMA GEMM: C[M,N] = A[M,K] @ W[N,K]^T + bias.  (unchanged from round 1)
// ---------------------------------------------------------------------------
template<typename AT, typename CT>
__global__ __launch_bounds__(256, 2)
void gemm_mfma(const AT* __restrict__ A, const float* __restrict__ W,
               const float* __restrict__ bias, CT* __restrict__ Cout,
               int M, int N, int K)
{
    __shared__ alignas(16) u32 As32[128 * 32];   // [row][8 slots of 16B], swizzled
    __shared__ alignas(16) u32 Bs32[64 * 32];

    const int tid  = threadIdx.x;
    const int lane = tid & 63;
    const int wave = tid >> 6;        // 0..3
    const int wm   = wave >> 1;       // 0..1 -> m offset 64*wm
    const int wn   = wave & 1;        // 0..1 -> n offset 32*wn
    const int m0   = blockIdx.y * 128;
    const int n0   = blockIdx.x * 64;
    const int lr   = lane & 15;       // fragment row/col
    const int lg   = lane >> 4;       // k-group 0..3

    floatx4 acc[4][2] = {};

    for (int kc = 0; kc < K; kc += 64) {
        // ---- stage A: 128 rows x 64 f16 = 1024 x 16B slots, 4 iters ----
        #pragma unroll
        for (int it = 0; it < 4; ++it) {
            const int s    = it * 256 + tid;
            const int row  = s >> 3;          // 0..127
            const int slot = s & 7;           // 0..7 (8 f16 each)
            const AT* src  = A + (size_t)(m0 + row) * K + kc + slot * 8;
            half8_t v;
            if constexpr (sizeof(AT) == 2) {
                v = *reinterpret_cast<const half8_t*>(src);
            } else {
                const float4* s4 = reinterpret_cast<const float4*>(src);
                float4 lo = s4[0], hi = s4[1];
                v[0] = (_Float16)lo.x; v[1] = (_Float16)lo.y;
                v[2] = (_Float16)lo.z; v[3] = (_Float16)lo.w;
                v[4] = (_Float16)hi.x; v[5] = (_Float16)hi.y;
                v[6] = (_Float16)hi.z; v[7] = (_Float16)hi.w;
            }
            const int sw = slot ^ (row & 7);
            *reinterpret_cast<half8_t*>(&As32[row * 32 + sw * 4]) = v;
        }
        // ---- stage B: 64 rows x 64 f16 = 512 slots, 2 iters (fp32 W) ----
        #pragma unroll
        for (int it = 0; it < 2; ++it) {
            const int s    = it * 256 + tid;
            const int row  = s >> 3;          // 0..63
            const int slot = s & 7;
            const float* src = W + (size_t)(n0 + row) * K + kc + slot * 8;
            const float4* s4 = reinterpret_cast<const float4*>(src);
            float4 lo = s4[0], hi = s4[1];
            half8_t v;
            v[0] = (_Float16)lo.x; v[1] = (_Float16)lo.y;
            v[2] = (_Float16)lo.z; v[3] = (_Float16)lo.w;
            v[4] = (_Float16)hi.x; v[5] = (_Float16)hi.y;
            v[6] = (_Float16)hi.z; v[7] = (_Float16)hi.w;
            const int sw = slot ^ (row & 7);
            *reinterpret_cast<half8_t*>(&Bs32[row * 32 + sw * 4]) = v;
        }
        __syncthreads();

        #pragma unroll
        for (int ks = 0; ks < 2; ++ks) {
            half8_t af[4], bf[2];
            #pragma unroll
            for (int fm = 0; fm < 4; ++fm) {
                const int row  = wm * 64 + fm * 16 + lr;
                const int slot = ks * 4 + lg;
                const int sw   = slot ^ (row & 7);
                af[fm] = *reinterpret_cast<const half8_t*>(&As32[row * 32 + sw * 4]);
            }
            #pragma unroll
            for (int fn = 0; fn < 2; ++fn) {
                const int row  = wn * 32 + fn * 16 + lr;
                const int slot = ks * 4 + lg;
                const int sw   = slot ^ (row & 7);
                bf[fn] = *reinterpret_cast<const half8_t*>(&Bs32[row * 32 + sw * 4]);
            }
            #pragma unroll
            for (int fm = 0; fm < 4; ++fm)
                #pragma unroll
                for (int fn = 0; fn < 2; ++fn)
                    acc[fm][fn] = __builtin_amdgcn_mfma_f32_16x16x32_f16(
                        af[fm], bf[fn], acc[fm][fn], 0, 0, 0);
        }
        __syncthreads();
    }

    // ---- epilogue: D[row=(lane>>4)*4+reg][col=lane&15] + bias ----
    #pragma unroll
    for (int fn = 0; fn < 2; ++fn) {
        const int n = n0 + wn * 32 + fn * 16 + lr;
        const float bv = bias[n];
        #pragma unroll
        for (int fm = 0; fm < 4; ++fm) {
            #pragma unroll
            for (int r = 0; r < 4; ++r) {
                const int m = m0 + wm * 64 + fm * 16 + lg * 4 + r;
                Cout[(size_t)m * N + n] = (CT)(acc[fm][fn][r] + bv);
            }
        }
    }
}

// ---------------------------------------------------------------------------
// Persistent GRU scan, v2. One WG per batch, 1024 threads = 16 waves
// (4 waves/SIMD for latency hiding; grid=64 so only 64 CUs are usable).
// Thread t: row j = t>>2 (0..255), k-quarter kq = t&3 (64 h values).
// Weights for rows {j, 256+j, 512+j}, k in [kq*64, kq*64+64): 96 half2 regs
// -> total VGPR demand ~125, fits the 128-reg / 4-wave-per-SIMD budget
// (v1's 192 weight regs forced AGPR banking + accvgpr_read per dot).
// h double-buffered in LDS -> ONE barrier per step. Quad k-reduction via
// DPP quad_perm (pure VALU). Sigmoid/tanh via v_exp + v_rcp (no precise-div
// sequences). Next-step g prefetched a full step early (the final step's
// prefetch overruns into the adjacent hbuf workspace region - valid memory).
// ---------------------------------------------------------------------------
__global__ __launch_bounds__(1024, 4)
void gru_scan(const _Float16* __restrict__ gx,   // [B, T, 768] incl. b_ih
              const float* __restrict__ Whh,     // [768, 256]
              const float* __restrict__ bhh,     // [768]
              _Float16* __restrict__ hout)       // [B, T, 256]
{
    const int b  = blockIdx.x;
    const int t  = threadIdx.x;
    const int j  = t >> 2;          // row 0..255
    const int kq = t & 3;           // k-quarter 0..3

    half2_t w0[32], w1[32], w2[32];
    {
        const float* p0 = Whh + (size_t)j * HH + kq * 64;
        const float* p1 = p0 + 256 * HH;
        const float* p2 = p0 + 512 * HH;
        #pragma unroll
        for (int i = 0; i < 32; ++i) {
            w0[i] = half2_t{(_Float16)p0[2*i], (_Float16)p0[2*i+1]};
            w1[i] = half2_t{(_Float16)p1[2*i], (_Float16)p1[2*i+1]};
            w2[i] = half2_t{(_Float16)p2[2*i], (_Float16)p2[2*i+1]};
        }
    }
    const float bh_r = bhh[j], bh_z = bhh[HH + j], bh_n = bhh[2*HH + j];

    __shared__ alignas(16) _Float16 hs[2][HH];   // double-buffered h (2x512B)
    if (t < HH/2) reinterpret_cast<u32*>(hs[0])[t] = 0u;
    float hprev = 0.f;

    const _Float16* gj = gx + (size_t)b * TT * G3 + j;
    _Float16* op = hout + (size_t)b * TT * HH + j;

    // prologue: step-0 input gates
    float xr = (float)gj[0];
    float xz = (float)gj[HH];
    float xn = (float)gj[2*HH];
    __syncthreads();

    for (int step = 0; step < TT; ++step) {
        // issue next step's g loads now; consumed after the barrier
        const _Float16* gn = gj + G3;
        const _Float16 pxr = gn[0];
        const _Float16 pxz = gn[HH];
        const _Float16 pxn = gn[2*HH];

        // 8 x ds_read_b128 over this thread's k-quarter (64 h values)
        const uint4* hb = reinterpret_cast<const uint4*>(hs[step & 1] + kq * 64);
        float ar = 0.f, az = 0.f, an = 0.f;
        #pragma unroll
        for (int c = 0; c < 8; ++c) {
            const uint4 hv = hb[c];
            const half2_t ha = bch2(hv.x), hc = bch2(hv.y);
            const half2_t hd = bch2(hv.z), he = bch2(hv.w);
            ar = dot2f(ha, w0[4*c+0], ar); az = dot2f(ha, w1[4*c+0], az); an = dot2f(ha, w2[4*c+0], an);
            ar = dot2f(hc, w0[4*c+1], ar); az = dot2f(hc, w1[4*c+1], az); an = dot2f(hc, w2[4*c+1], an);
            ar = dot2f(hd, w0[4*c+2], ar); az = dot2f(hd, w1[4*c+2], az); an = dot2f(hd, w2[4*c+2], an);
            ar = dot2f(he, w0[4*c+3], ar); az = dot2f(he, w1[4*c+3], az); an = dot2f(he, w2[4*c+3], an);
        }
        // k-quarter butterfly: all 4 quad lanes end with the full-k sums
        ar = quad_allsum(ar);
        az = quad_allsum(az);
        an = quad_allsum(an);

        const float r = fast_rcp(1.f + __expf(-(xr + ar + bh_r)));
        const float z = fast_rcp(1.f + __expf(-(xz + az + bh_z)));
        const float e = __expf(2.f * (xn + r * (an + bh_n)));
        const float nn = 1.f - 2.f * fast_rcp(e + 1.f);
        const float hnew = (1.f - z) * nn + z * hprev;
        hprev = hnew;

        if (kq == 0) {
            hs[(step + 1) & 1][j] = (_Float16)hnew;   // next step's buffer
            op[0] = (_Float16)hnew;                   // layer output (f16)
        }
        __syncthreads();   // writes to hs[(step+1)&1] visible; reads of hs[step&1] done

        gj = gn; op += HH;
        xr = (float)pxr; xz = (float)pxz; xn = (float)pxn;
    }
}

// ---------------------------------------------------------------------------
extern "C" void kernel_launch(void* const* d_in, const int* in_sizes, int n_in,
                              void* d_out, int out_size, void* d_ws, size_t ws_size,
                              hipStream_t stream) {
    const float* x    = (const float*)d_in[0];
    const float* Wih0 = (const float*)d_in[1];
    const float* Whh0 = (const float*)d_in[2];
    const float* bih0 = (const float*)d_in[3];
    const float* bhh0 = (const float*)d_in[4];
    const float* Wih1 = (const float*)d_in[5];
    const float* Whh1 = (const float*)d_in[6];
    const float* bih1 = (const float*)d_in[7];
    const float* bhh1 = (const float*)d_in[8];
    const float* fcw  = (const float*)d_in[9];
    const float* fcb  = (const float*)d_in[10];
    float* out = (float*)d_out;

    // workspace: gx buffer (201 MB, reused for both layers) + h buffer (64 MB)
    _Float16* gxbuf = (_Float16*)d_ws;
    _Float16* hbuf  = (_Float16*)((char*)d_ws + (size_t)MTOT * G3 * sizeof(_Float16));

    const dim3 blk(256);
    // 1) gx0 = x @ W_ih0^T + b_ih0
    gemm_mfma<float, _Float16><<<dim3(G3/64, MTOT/128), blk, 0, stream>>>(
        x, Wih0, bih0, gxbuf, MTOT, G3, II);
    // 2) scan layer 0 -> h0
    gru_scan<<<dim3(BB), dim3(1024), 0, stream>>>(gxbuf, Whh0, bhh0, hbuf);
    // 3) gx1 = h0 @ W_ih1^T + b_ih1 (overwrites gx buffer)
    gemm_mfma<_Float16, _Float16><<<dim3(G3/64, MTOT/128), blk, 0, stream>>>(
        hbuf, Wih1, bih1, gxbuf, MTOT, G3, HH);
    // 4) scan layer 1 -> h1 (overwrites h buffer)
    gru_scan<<<dim3(BB), dim3(1024), 0, stream>>>(gxbuf, Whh1, bhh1, hbuf);
    // 5) out = h1 @ fc_w^T + fc_b
    gemm_mfma<_Float16, float><<<dim3(CC/64, MTOT/128), blk, 0, stream>>>(
        hbuf, fcw, fcb, out, MTOT, CC, HH);
}